// Round 4
// baseline (3653.465 us; speedup 1.0000x reference)
//
#include <hip/hip_runtime.h>

// EncoderDecoderLSTM on MI355X — R4: R3 + occupancy doubling.
// BT 16->8, grid 256->512 blocks = 2 independent blocks/CU, 4 waves/SIMD.
// Two blocks' barriers are independent -> one block's waves fill the other's
// barrier/dependency stalls (R3 measured 42% VALU-idle at 2 waves/SIMD).
// MFMA M-rows 8-15 compute garbage confined to invalid batch rows (bounded,
// never stored). Math identical to R3: layer-pipelined (waves 0-3 layer0 slot s,
// waves 4-7 layer1 slot s-1), one barrier/slot, f16 hi+lo split (3 MFMAs/term),
// native v_exp/v_rcp activations, c-state fp32 in regs.

typedef _Float16 f16x8 __attribute__((ext_vector_type(8)));
typedef float    f32x4 __attribute__((ext_vector_type(4)));

static constexpr int T_ENC = 365;
static constexpr int HZ    = 7;
static constexpr int BT    = 8;    // valid batch rows per block
static constexpr int BROWS = 16;   // MFMA M rows (8-15 garbage, confined)
static constexpr int HPAD  = 72;   // padded f16 row stride (144 B)

#if __has_builtin(__builtin_amdgcn_exp2f)
__device__ __forceinline__ float fexp2(float x) { return __builtin_amdgcn_exp2f(x); }
#else
__device__ __forceinline__ float fexp2(float x) { return __exp2f(x); }
#endif
#if __has_builtin(__builtin_amdgcn_rcpf)
__device__ __forceinline__ float frcp(float x) { return __builtin_amdgcn_rcpf(x); }
#else
__device__ __forceinline__ float frcp(float x) { return 1.0f / x; }
#endif

// sigmoid: rcp(1+2^(-x*log2e)). Tails exact (exp2 inf->rcp 0; exp2 0->1).
__device__ __forceinline__ float sigf(float v) {
  return frcp(1.0f + fexp2(v * -1.442695040888963f));
}
// tanh: (t-1)*rcp(t+1), t=2^(2x*log2e). Clamp +-30 so t stays finite.
__device__ __forceinline__ float tanh_fast(float v) {
  v = fminf(fmaxf(v, -30.0f), 30.0f);
  float t = fexp2(v * 2.885390081777927f);
  return (t - 1.0f) * frcp(t + 1.0f);
}

// acc += (Ahi+Alo)*(Whi+Wlo), dropping lo*lo (~2^-22)
__device__ __forceinline__ f32x4 mm3(f16x8 ahi, f16x8 alo, f16x8 whi, f16x8 wlo, f32x4 acc) {
  acc = __builtin_amdgcn_mfma_f32_16x16x32_f16(ahi, whi, acc, 0, 0, 0);
  acc = __builtin_amdgcn_mfma_f32_16x16x32_f16(ahi, wlo, acc, 0, 0, 0);
  acc = __builtin_amdgcn_mfma_f32_16x16x32_f16(alo, whi, acc, 0, 0, 0);
  return acc;
}

__global__ __launch_bounds__(512, 4)
void lstm_fused(const float* __restrict__ x,
                const float* __restrict__ eWih0, const float* __restrict__ eWhh0,
                const float* __restrict__ eb0,
                const float* __restrict__ eWih1, const float* __restrict__ eWhh1,
                const float* __restrict__ eb1,
                const float* __restrict__ dWih0, const float* __restrict__ dWhh0,
                const float* __restrict__ db0,
                const float* __restrict__ dWih1, const float* __restrict__ dWhh1,
                const float* __restrict__ db1,
                const float* __restrict__ fcW, const float* __restrict__ fcb,
                float* __restrict__ out)
{
  __shared__ __align__(16) float    xs[T_ENC * BROWS];              // x transposed [t][b], rows 8-15 zero
  __shared__ __align__(16) _Float16 h0hi[2][BROWS * HPAD], h0lo[2][BROWS * HPAD];
  __shared__ __align__(16) _Float16 h1hi[2][BROWS * HPAD], h1lo[2][BROWS * HPAD];
  __shared__ __align__(16) float    dins[BROWS];

  const int tid  = threadIdx.x;
  const int lane = tid & 63;
  const int wv   = tid >> 6;        // wave 0..7; 0-3 = layer0 group, 4-7 = layer1 group
  const int wg   = wv & 3;          // index within group
  const int n    = lane & 15;       // tile col (gate row) / A-row (batch) index
  const int q    = lane >> 4;       // quad
  const int b0g  = blockIdx.x * BT;
  const int wbase = wg * 16 + n;    // D-layout j column for h writes

  // Stage x[b][t] -> xs[t][b]; rows 8-15 zero (garbage-row inputs stay finite)
  for (int i = tid; i < T_ENC * BROWS; i += 512) {
    int b = i / T_ENC;
    int t = i - b * T_ENC;
    xs[t * BROWS + b] = (b < BT) ? x[(b0g + b) * T_ENC + t] : 0.f;
  }
  for (int i = tid; i < 2 * BROWS * HPAD; i += 512) {
    ((_Float16*)h0hi)[i] = (_Float16)0.f; ((_Float16*)h0lo)[i] = (_Float16)0.f;
    ((_Float16*)h1hi)[i] = (_Float16)0.f; ((_Float16*)h1lo)[i] = (_Float16)0.f;
  }
  if (tid < BROWS) dins[tid] = 0.f;

  // Weight registers (shared pool between groups):
  //   group A (layer0): WA = Whh0 ;               wih0v = Wih0 col, biasv = b0
  //   group B (layer1): WA = Wih1 ; WB = Whh1 ;   biasv = b1
  f16x8 WAhi[4][2], WAlo[4][2], WBhi[4][2], WBlo[4][2];
  float biasv[4], wih0v[4];

  auto splitrow = [&](const float* p, f16x8& hi, f16x8& lo) {
    #pragma unroll
    for (int j = 0; j < 8; ++j) {
      float v = p[j];
      _Float16 h = (_Float16)v;
      hi[j] = h; lo[j] = (_Float16)(v - (float)h);
    }
  };
  auto loadA = [&](const float* Wih0_, const float* Whh0_, const float* b0_) {
    #pragma unroll
    for (int ti = 0; ti < 4; ++ti) {
      const int r = (ti * 4 + wg) * 16 + n;
      biasv[ti] = b0_[r];
      wih0v[ti] = Wih0_[r];
      #pragma unroll
      for (int kc = 0; kc < 2; ++kc)
        splitrow(Whh0_ + r * 64 + kc * 32 + q * 8, WAhi[ti][kc], WAlo[ti][kc]);
    }
  };
  auto loadB = [&](const float* Wih1_, const float* Whh1_, const float* b1_) {
    #pragma unroll
    for (int ti = 0; ti < 4; ++ti) {
      const int r = (ti * 4 + wg) * 16 + n;
      biasv[ti] = b1_[r];
      #pragma unroll
      for (int kc = 0; kc < 2; ++kc) {
        splitrow(Wih1_ + r * 64 + kc * 32 + q * 8, WAhi[ti][kc], WAlo[ti][kc]);
        splitrow(Whh1_ + r * 64 + kc * 32 + q * 8, WBhi[ti][kc], WBlo[ti][kc]);
      }
    }
  };

  if (wv < 4) loadA(eWih0, eWhh0, eb0);
  else        loadB(eWih1, eWhh1, eb1);

  f32x4 cst = {0.f, 0.f, 0.f, 0.f};   // c0 on group A, c1 on group B

  // layer0 step: h_new = lstm(x_in, h_prev) ; gates = bias + x*wih0 + h@WA^T
  auto stepA = [&](const _Float16* Hhi, const _Float16* Hlo,
                   _Float16* Ohi, _Float16* Olo, f32x4 xv) {
    const _Float16* hp = Hhi + n * HPAD;
    const _Float16* lp = Hlo + n * HPAD;
    f16x8 ah0 = *(const f16x8*)(hp + q * 8);
    f16x8 ah1 = *(const f16x8*)(hp + 32 + q * 8);
    f16x8 al0 = *(const f16x8*)(lp + q * 8);
    f16x8 al1 = *(const f16x8*)(lp + 32 + q * 8);
    f32x4 g[4];
    #pragma unroll
    for (int ti = 0; ti < 4; ++ti) {
      f32x4 a;
      #pragma unroll
      for (int r = 0; r < 4; ++r) a[r] = xv[r] * wih0v[ti] + biasv[ti];
      a = mm3(ah0, al0, WAhi[ti][0], WAlo[ti][0], a);
      a = mm3(ah1, al1, WAhi[ti][1], WAlo[ti][1], a);
      g[ti] = a;
    }
    #pragma unroll
    for (int r = 0; r < 4; ++r) {
      float c = sigf(g[1][r]) * cst[r] + sigf(g[0][r]) * tanh_fast(g[2][r]);
      cst[r] = c;
      float h = sigf(g[3][r]) * tanh_fast(c);
      _Float16 hi = (_Float16)h;
      Ohi[(q * 4 + r) * HPAD + wbase] = hi;
      Olo[(q * 4 + r) * HPAD + wbase] = (_Float16)(h - (float)hi);
    }
  };

  // layer1 step: gates = bias + h0@WA^T + h1@WB^T
  auto stepB = [&](const _Float16* H0hi, const _Float16* H0lo,
                   const _Float16* H1hi, const _Float16* H1lo,
                   _Float16* Ohi, _Float16* Olo) {
    const _Float16* p0h = H0hi + n * HPAD;
    const _Float16* p0l = H0lo + n * HPAD;
    const _Float16* p1h = H1hi + n * HPAD;
    const _Float16* p1l = H1lo + n * HPAD;
    f16x8 b0h0 = *(const f16x8*)(p0h + q * 8);
    f16x8 b0h1 = *(const f16x8*)(p0h + 32 + q * 8);
    f16x8 b0l0 = *(const f16x8*)(p0l + q * 8);
    f16x8 b0l1 = *(const f16x8*)(p0l + 32 + q * 8);
    f16x8 a1h0 = *(const f16x8*)(p1h + q * 8);
    f16x8 a1h1 = *(const f16x8*)(p1h + 32 + q * 8);
    f16x8 a1l0 = *(const f16x8*)(p1l + q * 8);
    f16x8 a1l1 = *(const f16x8*)(p1l + 32 + q * 8);
    f32x4 g[4];
    #pragma unroll
    for (int ti = 0; ti < 4; ++ti) {
      f32x4 a;
      #pragma unroll
      for (int r = 0; r < 4; ++r) a[r] = biasv[ti];
      a = mm3(b0h0, b0l0, WAhi[ti][0], WAlo[ti][0], a);
      a = mm3(b0h1, b0l1, WAhi[ti][1], WAlo[ti][1], a);
      a = mm3(a1h0, a1l0, WBhi[ti][0], WBlo[ti][0], a);
      a = mm3(a1h1, a1l1, WBhi[ti][1], WBlo[ti][1], a);
      g[ti] = a;
    }
    #pragma unroll
    for (int r = 0; r < 4; ++r) {
      float c = sigf(g[1][r]) * cst[r] + sigf(g[0][r]) * tanh_fast(g[2][r]);
      cst[r] = c;
      float h = sigf(g[3][r]) * tanh_fast(c);
      _Float16 hi = (_Float16)h;
      Ohi[(q * 4 + r) * HPAD + wbase] = hi;
      Olo[(q * 4 + r) * HPAD + wbase] = (_Float16)(h - (float)hi);
    }
  };

  __syncthreads();

  // ---- encoder: slots s=0..365. A computes h0(s) for s<365; B computes h1(s-1) for s>=1.
  // h0(t) lives in buffer t&1; h1(t) in buffer t&1. One barrier per slot.
  #pragma unroll 1
  for (int s = 0; s <= T_ENC; ++s) {
    if (wv < 4) {
      if (s < T_ENC) {
        const int cur = s & 1, prv = cur ^ 1;
        f32x4 xv = *(const f32x4*)(xs + s * BROWS + q * 4);
        stepA(h0hi[prv], h0lo[prv], h0hi[cur], h0lo[cur], xv);
      } else {
        loadA(dWih0, dWhh0, db0);   // free overlap: A idle in last slot
      }
    } else {
      if (s >= 1) {
        const int t = s - 1;
        const int w1 = t & 1, r1 = w1 ^ 1;
        stepB(h0hi[t & 1], h0lo[t & 1], h1hi[r1], h1lo[r1], h1hi[w1], h1lo[w1]);
      }
    }
    __syncthreads();
  }

  // ---- decoder ----
  if (wv >= 4) loadB(dWih1, dWhh1, db1);
  float fcw[16];
  #pragma unroll
  for (int j = 0; j < 16; ++j) fcw[j] = fcW[q * 16 + j];
  const float fcb0 = fcb[0];
  // encoder left latest h0 (t=364) and h1 (t=364) in buffer 0.

  #pragma unroll 1
  for (int hz = 0; hz < HZ; ++hz) {
    const int p = hz & 1;           // latest state parity at step entry
    if (wv < 4) {
      f32x4 dv = *(const f32x4*)(dins + q * 4);
      stepA(h0hi[p], h0lo[p], h0hi[1 - p], h0lo[1 - p], dv);
    }
    __syncthreads();
    if (wv >= 4) {
      stepB(h0hi[1 - p], h0lo[1 - p], h1hi[p], h1lo[p], h1hi[1 - p], h1lo[1 - p]);
    }
    __syncthreads();
    if (wv == 0) {
      const _Float16* Hhi = h1hi[1 - p];
      const _Float16* Hlo = h1lo[1 - p];
      f16x8 hh0 = *(const f16x8*)(Hhi + n * HPAD + q * 16);
      f16x8 hh1 = *(const f16x8*)(Hhi + n * HPAD + q * 16 + 8);
      f16x8 hl0 = *(const f16x8*)(Hlo + n * HPAD + q * 16);
      f16x8 hl1 = *(const f16x8*)(Hlo + n * HPAD + q * 16 + 8);
      float pacc = 0.f;
      #pragma unroll
      for (int j = 0; j < 8; ++j) pacc += fcw[j] * ((float)hh0[j] + (float)hl0[j]);
      #pragma unroll
      for (int j = 0; j < 8; ++j) pacc += fcw[8 + j] * ((float)hh1[j] + (float)hl1[j]);
      pacc += __shfl_down(pacc, 32);
      pacc += __shfl_down(pacc, 16);
      if (lane < BT) {
        pacc += fcb0;
        out[(b0g + lane) * HZ + hz] = pacc;
        dins[lane] = pacc;
      }
    }
    __syncthreads();
  }
}

extern "C" void kernel_launch(void* const* d_in, const int* in_sizes, int n_in,
                              void* d_out, int out_size, void* d_ws, size_t ws_size,
                              hipStream_t stream) {
  (void)in_sizes; (void)n_in; (void)d_ws; (void)ws_size; (void)out_size;
  const float* x     = (const float*)d_in[0];
  const float* eWih0 = (const float*)d_in[1];
  const float* eWhh0 = (const float*)d_in[2];
  const float* eb0   = (const float*)d_in[3];
  const float* eWih1 = (const float*)d_in[4];
  const float* eWhh1 = (const float*)d_in[5];
  const float* eb1   = (const float*)d_in[6];
  const float* dWih0 = (const float*)d_in[7];
  const float* dWhh0 = (const float*)d_in[8];
  const float* db0   = (const float*)d_in[9];
  const float* dWih1 = (const float*)d_in[10];
  const float* dWhh1 = (const float*)d_in[11];
  const float* db1   = (const float*)d_in[12];
  const float* fcW   = (const float*)d_in[13];
  const float* fcb   = (const float*)d_in[14];
  float* out = (float*)d_out;

  dim3 grid(4096 / BT);   // 512 blocks = 2 per CU
  dim3 block(512);        // 8 waves: 4 layer0 + 4 layer1
  hipLaunchKernelGGL(lstm_fused, grid, block, 0, stream,
                     x, eWih0, eWhh0, eb0, eWih1, eWhh1, eb1,
                     dWih0, dWhh0, db0, dWih1, dWhh1, db1, fcW, fcb, out);
}

// Round 5
// 871.439 us; speedup vs baseline: 4.1924x; 4.1924x over previous
//
#include <hip/hip_runtime.h>

// EncoderDecoderLSTM on MI355X — R5: gate-split 16-wave layer pipeline.
// 1024 thr/block, BT=16, grid 256 (1 block/CU, 4 waves/SIMD).
// Waves 0-7: layer0 at slot s; waves 8-15: layer1 at slot s-1.
// Within a layer group of 8: wg = j-tile (0..3), half: 0 -> gates i,f ; 1 -> g,o.
// Per-wave: 2 gate-tiles of gates[16b x 256r] = h[16x64] @ W^T (mfma 16x16x32 f16,
// hi+lo split on h and primary W; Whh1 held hi-only to fit 128-VGPR budget).
// Activation split by acc row via one LDS float2 exchange; 2 barriers/slot.
// R4 lesson: f16x8 = 4 VGPRs; total (VGPR+AGPR) must be <=128 for 4 waves/SIMD.
// amdgpu_waves_per_eu(4,4) pins the allocator (R4's (512,4) let it target 64 -> 13GB spill).

typedef _Float16 f16x8 __attribute__((ext_vector_type(8)));
typedef float    f32x4 __attribute__((ext_vector_type(4)));

static constexpr int T_ENC = 365;
static constexpr int HZ    = 7;
static constexpr int BT    = 16;   // batch rows per block
static constexpr int HPAD  = 72;   // padded f16 row stride (144 B)
static constexpr int EXP2  = 65;   // exch row stride in float2 (520 B -> bank-spread)

#if __has_builtin(__builtin_amdgcn_exp2f)
__device__ __forceinline__ float fexp2(float x) { return __builtin_amdgcn_exp2f(x); }
#else
__device__ __forceinline__ float fexp2(float x) { return __exp2f(x); }
#endif
#if __has_builtin(__builtin_amdgcn_rcpf)
__device__ __forceinline__ float frcp(float x) { return __builtin_amdgcn_rcpf(x); }
#else
__device__ __forceinline__ float frcp(float x) { return 1.0f / x; }
#endif

__device__ __forceinline__ float sigf(float v) {
  return frcp(1.0f + fexp2(v * -1.442695040888963f));
}
__device__ __forceinline__ float tanh_fast(float v) {
  v = fminf(fmaxf(v, -30.0f), 30.0f);
  float t = fexp2(v * 2.885390081777927f);
  return (t - 1.0f) * frcp(t + 1.0f);
}

// acc += (Ahi+Alo)*(Whi+Wlo) dropping lo*lo
__device__ __forceinline__ f32x4 mm3(f16x8 ahi, f16x8 alo, f16x8 whi, f16x8 wlo, f32x4 acc) {
  acc = __builtin_amdgcn_mfma_f32_16x16x32_f16(ahi, whi, acc, 0, 0, 0);
  acc = __builtin_amdgcn_mfma_f32_16x16x32_f16(ahi, wlo, acc, 0, 0, 0);
  acc = __builtin_amdgcn_mfma_f32_16x16x32_f16(alo, whi, acc, 0, 0, 0);
  return acc;
}
// acc += (Ahi+Alo)*Whi  (W held hi-only)
__device__ __forceinline__ f32x4 mm2(f16x8 ahi, f16x8 alo, f16x8 whi, f32x4 acc) {
  acc = __builtin_amdgcn_mfma_f32_16x16x32_f16(ahi, whi, acc, 0, 0, 0);
  acc = __builtin_amdgcn_mfma_f32_16x16x32_f16(alo, whi, acc, 0, 0, 0);
  return acc;
}

__global__ __launch_bounds__(1024) __attribute__((amdgpu_waves_per_eu(4, 4)))
void lstm_fused(const float* __restrict__ x,
                const float* __restrict__ eWih0, const float* __restrict__ eWhh0,
                const float* __restrict__ eb0,
                const float* __restrict__ eWih1, const float* __restrict__ eWhh1,
                const float* __restrict__ eb1,
                const float* __restrict__ dWih0, const float* __restrict__ dWhh0,
                const float* __restrict__ db0,
                const float* __restrict__ dWih1, const float* __restrict__ dWhh1,
                const float* __restrict__ db1,
                const float* __restrict__ fcW, const float* __restrict__ fcb,
                float* __restrict__ out)
{
  __shared__ __align__(16) float    xs[T_ENC * BT];
  __shared__ __align__(16) _Float16 h0hi[2][BT * HPAD], h0lo[2][BT * HPAD];
  __shared__ __align__(16) _Float16 h1hi[2][BT * HPAD], h1lo[2][BT * HPAD];
  __shared__ __align__(16) float2   exch[2][16 * EXP2];
  __shared__ __align__(16) float    dins[BT];

  const int tid  = threadIdx.x;
  const int lane = tid & 63;
  const int wv   = tid >> 6;        // 0..15
  const int L    = wv >> 3;         // 0 = layer0 group, 1 = layer1 group
  const int w8   = wv & 7;
  const int wg   = w8 & 3;          // j-tile
  const int half = w8 >> 2;         // 0: gates i,f ; 1: gates g,o
  const int n    = lane & 15;
  const int q    = lane >> 4;
  const int b0g  = blockIdx.x * BT;
  const int wbase = wg * 16 + n;    // j column
  const int row0  = q * 4;          // lane's base acc row

  // Stage x[b][t] -> xs[t][b]
  for (int i = tid; i < T_ENC * BT; i += 1024) {
    int b = i / T_ENC;
    int t = i - b * T_ENC;
    xs[t * BT + b] = x[(b0g + b) * T_ENC + t];
  }
  for (int i = tid; i < 2 * BT * HPAD; i += 1024) {
    ((_Float16*)h0hi)[i] = (_Float16)0.f; ((_Float16*)h0lo)[i] = (_Float16)0.f;
    ((_Float16*)h1hi)[i] = (_Float16)0.f; ((_Float16*)h1lo)[i] = (_Float16)0.f;
  }
  if (tid < BT) dins[tid] = 0.f;

  // Per-wave weights (2 gate-tiles):
  //  L0: Whi/Wlo = Whh0 rows ; wih0v = Wih0 col ; biasv = b0
  //  L1: Whi/Wlo = Wih1 ; W2hi = Whh1 (hi only) ; biasv = b1
  f16x8 Whi[2][2], Wlo[2][2], W2hi[2][2];
  float biasv[2], wih0v[2];

  auto splitrow = [&](const float* p, f16x8& hi, f16x8& lo) {
    #pragma unroll
    for (int j = 0; j < 8; ++j) {
      float v = p[j];
      _Float16 h = (_Float16)v;
      hi[j] = h; lo[j] = (_Float16)(v - (float)h);
    }
  };
  auto cvtrow = [&](const float* p, f16x8& hi) {
    #pragma unroll
    for (int j = 0; j < 8; ++j) hi[j] = (_Float16)p[j];
  };
  auto loadA = [&](const float* Wih0_, const float* Whh0_, const float* b0_) {
    #pragma unroll
    for (int ti = 0; ti < 2; ++ti) {
      const int r = ((half * 2 + ti) * 4 + wg) * 16 + n;
      biasv[ti] = b0_[r];
      wih0v[ti] = Wih0_[r];
      #pragma unroll
      for (int kc = 0; kc < 2; ++kc)
        splitrow(Whh0_ + r * 64 + kc * 32 + q * 8, Whi[ti][kc], Wlo[ti][kc]);
    }
  };
  auto loadB = [&](const float* Wih1_, const float* Whh1_, const float* b1_) {
    #pragma unroll
    for (int ti = 0; ti < 2; ++ti) {
      const int r = ((half * 2 + ti) * 4 + wg) * 16 + n;
      biasv[ti] = b1_[r];
      #pragma unroll
      for (int kc = 0; kc < 2; ++kc) {
        splitrow(Wih1_ + r * 64 + kc * 32 + q * 8, Whi[ti][kc], Wlo[ti][kc]);
        cvtrow(Whh1_ + r * 64 + kc * 32 + q * 8, W2hi[ti][kc]);
      }
    }
  };

  if (L == 0) loadA(eWih0, eWhh0, eb0);
  else        loadB(eWih1, eWhh1, eb1);

  float cs0 = 0.f, cs1 = 0.f;   // c-state for this wave's 2 rows

  auto stepA_mm = [&](const _Float16* Hh, const _Float16* Hl, f32x4 xv, f32x4* g2) {
    const _Float16* hp = Hh + n * HPAD;
    const _Float16* lp = Hl + n * HPAD;
    f16x8 ah0 = *(const f16x8*)(hp + q * 8);
    f16x8 ah1 = *(const f16x8*)(hp + 32 + q * 8);
    f16x8 al0 = *(const f16x8*)(lp + q * 8);
    f16x8 al1 = *(const f16x8*)(lp + 32 + q * 8);
    #pragma unroll
    for (int ti = 0; ti < 2; ++ti) {
      f32x4 a;
      #pragma unroll
      for (int r = 0; r < 4; ++r) a[r] = xv[r] * wih0v[ti] + biasv[ti];
      a = mm3(ah0, al0, Whi[ti][0], Wlo[ti][0], a);
      a = mm3(ah1, al1, Whi[ti][1], Wlo[ti][1], a);
      g2[ti] = a;
    }
  };
  auto stepB_mm = [&](const _Float16* H0h, const _Float16* H0l,
                      const _Float16* H1h, const _Float16* H1l, f32x4* g2) {
    const _Float16* p0h = H0h + n * HPAD;
    const _Float16* p0l = H0l + n * HPAD;
    const _Float16* p1h = H1h + n * HPAD;
    const _Float16* p1l = H1l + n * HPAD;
    f16x8 b0h0 = *(const f16x8*)(p0h + q * 8);
    f16x8 b0h1 = *(const f16x8*)(p0h + 32 + q * 8);
    f16x8 b0l0 = *(const f16x8*)(p0l + q * 8);
    f16x8 b0l1 = *(const f16x8*)(p0l + 32 + q * 8);
    f16x8 a1h0 = *(const f16x8*)(p1h + q * 8);
    f16x8 a1h1 = *(const f16x8*)(p1h + 32 + q * 8);
    f16x8 a1l0 = *(const f16x8*)(p1l + q * 8);
    f16x8 a1l1 = *(const f16x8*)(p1l + 32 + q * 8);
    #pragma unroll
    for (int ti = 0; ti < 2; ++ti) {
      f32x4 a;
      #pragma unroll
      for (int r = 0; r < 4; ++r) a[r] = biasv[ti];
      a = mm3(b0h0, b0l0, Whi[ti][0], Wlo[ti][0], a);
      a = mm3(b0h1, b0l1, Whi[ti][1], Wlo[ti][1], a);
      a = mm2(a1h0, a1l0, W2hi[ti][0], a);
      a = mm2(a1h1, a1l1, W2hi[ti][1], a);
      g2[ti] = a;
    }
  };

  // act phase 1: transcendentals on own gates; ship the 2 rows the partner owns
  auto act_pre = [&](const f32x4* g2, float* sv0, float* sv1) {
    if (half == 0) {   // own i,f ; ship rows row0+2, row0+3
      #pragma unroll
      for (int r = 0; r < 4; ++r) { sv0[r] = sigf(g2[0][r]); sv1[r] = sigf(g2[1][r]); }
      exch[L][(row0 + 2) * EXP2 + wbase] = make_float2(sv0[2], sv1[2]);
      exch[L][(row0 + 3) * EXP2 + wbase] = make_float2(sv0[3], sv1[3]);
    } else {           // own g,o ; ship rows row0+0, row0+1
      #pragma unroll
      for (int r = 0; r < 4; ++r) { sv0[r] = tanh_fast(g2[0][r]); sv1[r] = sigf(g2[1][r]); }
      exch[L][(row0 + 0) * EXP2 + wbase] = make_float2(sv0[0], sv1[0]);
      exch[L][(row0 + 1) * EXP2 + wbase] = make_float2(sv0[1], sv1[1]);
    }
  };
  // act phase 2 (post-barrier): c/h update for this wave's 2 rows + h publish
  auto act_post = [&](const float* sv0, const float* sv1, _Float16* Oh, _Float16* Ol) {
    float si0, sf0, tg0, so0, si1, sf1, tg1, so1;
    int ra, rb;
    if (half == 0) {   // rows row0+0, row0+1 ; partner sent (tg, so)
      float2 e0 = exch[L][(row0 + 0) * EXP2 + wbase];
      float2 e1 = exch[L][(row0 + 1) * EXP2 + wbase];
      si0 = sv0[0]; sf0 = sv1[0]; tg0 = e0.x; so0 = e0.y;
      si1 = sv0[1]; sf1 = sv1[1]; tg1 = e1.x; so1 = e1.y;
      ra = row0; rb = row0 + 1;
    } else {           // rows row0+2, row0+3 ; partner sent (si, sf)
      float2 e0 = exch[L][(row0 + 2) * EXP2 + wbase];
      float2 e1 = exch[L][(row0 + 3) * EXP2 + wbase];
      si0 = e0.x; sf0 = e0.y; tg0 = sv0[2]; so0 = sv1[2];
      si1 = e1.x; sf1 = e1.y; tg1 = sv0[3]; so1 = sv1[3];
      ra = row0 + 2; rb = row0 + 3;
    }
    cs0 = sf0 * cs0 + si0 * tg0;
    float ha = so0 * tanh_fast(cs0);
    cs1 = sf1 * cs1 + si1 * tg1;
    float hb = so1 * tanh_fast(cs1);
    _Float16 pa = (_Float16)ha;
    Oh[ra * HPAD + wbase] = pa; Ol[ra * HPAD + wbase] = (_Float16)(ha - (float)pa);
    _Float16 pb = (_Float16)hb;
    Oh[rb * HPAD + wbase] = pb; Ol[rb * HPAD + wbase] = (_Float16)(hb - (float)pb);
  };

  __syncthreads();

  // ---- encoder: slots s=0..365; L0 computes h0(s) (s<365), L1 computes h1(s-1) (s>=1).
  #pragma unroll 1
  for (int s = 0; s <= T_ENC; ++s) {
    f32x4 g2[2];
    float sv0[4], sv1[4];
    const bool active = (L == 0) ? (s < T_ENC) : (s >= 1);
    if (L == 0) {
      if (s < T_ENC) {
        f32x4 xv = *(const f32x4*)(xs + s * BT + q * 4);
        const int prv = (s & 1) ^ 1;
        stepA_mm(h0hi[prv], h0lo[prv], xv, g2);
      } else {
        loadA(dWih0, dWhh0, db0);   // overlap decoder-weight load into idle slot
      }
    } else if (s >= 1) {
      const int t = s - 1;
      stepB_mm(h0hi[t & 1], h0lo[t & 1], h1hi[(t & 1) ^ 1], h1lo[(t & 1) ^ 1], g2);
    }
    if (active) act_pre(g2, sv0, sv1);
    __syncthreads();                 // exchange visible
    if (active) {
      if (L == 0) act_post(sv0, sv1, h0hi[s & 1], h0lo[s & 1]);
      else        act_post(sv0, sv1, h1hi[(s - 1) & 1], h1lo[(s - 1) & 1]);
    }
    __syncthreads();                 // h publish
  }

  // ---- decoder ----
  if (L == 1) loadB(dWih1, dWhh1, db1);
  const float fcb0 = fcb[0];
  // latest h0,h1 from t=364 live in parity-0 buffers.

  #pragma unroll 1
  for (int hz = 0; hz < HZ; ++hz) {
    const int p = hz & 1;
    f32x4 g2[2];
    float sv0[4], sv1[4];
    if (L == 0) {
      f32x4 dv = *(const f32x4*)(dins + q * 4);
      stepA_mm(h0hi[p], h0lo[p], dv, g2);
      act_pre(g2, sv0, sv1);
    }
    __syncthreads();
    if (L == 0) act_post(sv0, sv1, h0hi[1 - p], h0lo[1 - p]);
    __syncthreads();
    if (L == 1) {
      stepB_mm(h0hi[1 - p], h0lo[1 - p], h1hi[p], h1lo[p], g2);
      act_pre(g2, sv0, sv1);
    }
    __syncthreads();
    if (L == 1) act_post(sv0, sv1, h1hi[1 - p], h1lo[1 - p]);
    __syncthreads();
    if (wv == 0) {
      const _Float16* Hh = h1hi[1 - p];
      const _Float16* Hl = h1lo[1 - p];
      f16x8 hh0 = *(const f16x8*)(Hh + n * HPAD + q * 16);
      f16x8 hh1 = *(const f16x8*)(Hh + n * HPAD + q * 16 + 8);
      f16x8 hl0 = *(const f16x8*)(Hl + n * HPAD + q * 16);
      f16x8 hl1 = *(const f16x8*)(Hl + n * HPAD + q * 16 + 8);
      float pacc = 0.f;
      #pragma unroll
      for (int j = 0; j < 8; ++j) pacc += fcW[q * 16 + j] * ((float)hh0[j] + (float)hl0[j]);
      #pragma unroll
      for (int j = 0; j < 8; ++j) pacc += fcW[q * 16 + 8 + j] * ((float)hh1[j] + (float)hl1[j]);
      pacc += __shfl_down(pacc, 32);
      pacc += __shfl_down(pacc, 16);
      if (lane < BT) {
        pacc += fcb0;
        out[(b0g + lane) * HZ + hz] = pacc;
        dins[lane] = pacc;
      }
    }
    __syncthreads();
  }
}

extern "C" void kernel_launch(void* const* d_in, const int* in_sizes, int n_in,
                              void* d_out, int out_size, void* d_ws, size_t ws_size,
                              hipStream_t stream) {
  (void)in_sizes; (void)n_in; (void)d_ws; (void)ws_size; (void)out_size;
  const float* x     = (const float*)d_in[0];
  const float* eWih0 = (const float*)d_in[1];
  const float* eWhh0 = (const float*)d_in[2];
  const float* eb0   = (const float*)d_in[3];
  const float* eWih1 = (const float*)d_in[4];
  const float* eWhh1 = (const float*)d_in[5];
  const float* eb1   = (const float*)d_in[6];
  const float* dWih0 = (const float*)d_in[7];
  const float* dWhh0 = (const float*)d_in[8];
  const float* db0   = (const float*)d_in[9];
  const float* dWih1 = (const float*)d_in[10];
  const float* dWhh1 = (const float*)d_in[11];
  const float* db1   = (const float*)d_in[12];
  const float* fcW   = (const float*)d_in[13];
  const float* fcb   = (const float*)d_in[14];
  float* out = (float*)d_out;

  dim3 grid(4096 / BT);   // 256 blocks = 1/CU
  dim3 block(1024);       // 16 waves = 4 waves/SIMD
  hipLaunchKernelGGL(lstm_fused, grid, block, 0, stream,
                     x, eWih0, eWhh0, eb0, eWih1, eWhh1, eb1,
                     dWih0, dWhh0, db0, dWih1, dWhh1, db1, fcW, fcb, out);
}

// Round 6
// 570.745 us; speedup vs baseline: 6.4012x; 1.5268x over previous
//
#include <hip/hip_runtime.h>

// EncoderDecoderLSTM on MI355X — R6: R3 base + encoder slot loop unrolled x2.
// Buffer parity is compile-time -> all LDS addresses fold to base+immediate,
// parity selects vanish (R3-R5 analysis: ~400 cyc/wave/slot of re-derived
// addressing under '#pragma unroll 1' dynamic parity).
// Structure (proven in R3, 554 us): 512 thr, grid 256 (1 block/CU, 2 waves/SIMD,
// 256-reg budget -> no spill). Waves 0-3 layer0 slot s, waves 4-7 layer1 slot s-1,
// one barrier/slot, f16 hi+lo split (3 MFMAs/term), native v_exp/v_rcp
// activations, c-state fp32 in regs. R4/R5 lesson: 4 waves/SIMD = 128 TOTAL
// regs (VGPR+AGPR unified) -> guaranteed spill for this kernel; don't go there.

typedef _Float16 f16x8 __attribute__((ext_vector_type(8)));
typedef float    f32x4 __attribute__((ext_vector_type(4)));

static constexpr int T_ENC = 365;
static constexpr int HZ    = 7;
static constexpr int BT    = 16;   // batch tile per block
static constexpr int HPAD  = 72;   // padded f16 row stride (144 B)

#if __has_builtin(__builtin_amdgcn_exp2f)
__device__ __forceinline__ float fexp2(float x) { return __builtin_amdgcn_exp2f(x); }
#else
__device__ __forceinline__ float fexp2(float x) { return __exp2f(x); }
#endif
#if __has_builtin(__builtin_amdgcn_rcpf)
__device__ __forceinline__ float frcp(float x) { return __builtin_amdgcn_rcpf(x); }
#else
__device__ __forceinline__ float frcp(float x) { return 1.0f / x; }
#endif

// sigmoid: rcp(1+2^(-x*log2e)). Tails exact (exp2 inf->rcp 0; exp2 0->1).
__device__ __forceinline__ float sigf(float v) {
  return frcp(1.0f + fexp2(v * -1.442695040888963f));
}
// tanh: (t-1)*rcp(t+1), t=2^(2x*log2e). Clamp +-30 so t stays finite.
__device__ __forceinline__ float tanh_fast(float v) {
  v = fminf(fmaxf(v, -30.0f), 30.0f);
  float t = fexp2(v * 2.885390081777927f);
  return (t - 1.0f) * frcp(t + 1.0f);
}

// acc += (Ahi+Alo)*(Whi+Wlo), dropping lo*lo (~2^-22)
__device__ __forceinline__ f32x4 mm3(f16x8 ahi, f16x8 alo, f16x8 whi, f16x8 wlo, f32x4 acc) {
  acc = __builtin_amdgcn_mfma_f32_16x16x32_f16(ahi, whi, acc, 0, 0, 0);
  acc = __builtin_amdgcn_mfma_f32_16x16x32_f16(ahi, wlo, acc, 0, 0, 0);
  acc = __builtin_amdgcn_mfma_f32_16x16x32_f16(alo, whi, acc, 0, 0, 0);
  return acc;
}

__global__ __launch_bounds__(512, 2)
void lstm_fused(const float* __restrict__ x,
                const float* __restrict__ eWih0, const float* __restrict__ eWhh0,
                const float* __restrict__ eb0,
                const float* __restrict__ eWih1, const float* __restrict__ eWhh1,
                const float* __restrict__ eb1,
                const float* __restrict__ dWih0, const float* __restrict__ dWhh0,
                const float* __restrict__ db0,
                const float* __restrict__ dWih1, const float* __restrict__ dWhh1,
                const float* __restrict__ db1,
                const float* __restrict__ fcW, const float* __restrict__ fcb,
                float* __restrict__ out)
{
  __shared__ __align__(16) float    xs[T_ENC * BT];                 // x transposed [t][b]
  __shared__ __align__(16) _Float16 h0hi[2][BT * HPAD], h0lo[2][BT * HPAD];
  __shared__ __align__(16) _Float16 h1hi[2][BT * HPAD], h1lo[2][BT * HPAD];
  __shared__ __align__(16) float    dins[BT];

  const int tid  = threadIdx.x;
  const int lane = tid & 63;
  const int wv   = tid >> 6;        // wave 0..7; 0-3 = layer0 group, 4-7 = layer1 group
  const int wg   = wv & 3;          // index within group
  const int n    = lane & 15;       // tile col (gate row) / A-row (batch) index
  const int q    = lane >> 4;       // quad
  const int b0g  = blockIdx.x * BT;
  const int wbase = wg * 16 + n;    // D-layout j column for h writes

  // Stage x[b][t] -> xs[t][b]
  for (int i = tid; i < T_ENC * BT; i += 512) {
    int b = i / T_ENC;
    int t = i - b * T_ENC;
    xs[t * BT + b] = x[(b0g + b) * T_ENC + t];
  }
  for (int i = tid; i < 2 * BT * HPAD; i += 512) {
    ((_Float16*)h0hi)[i] = (_Float16)0.f; ((_Float16*)h0lo)[i] = (_Float16)0.f;
    ((_Float16*)h1hi)[i] = (_Float16)0.f; ((_Float16*)h1lo)[i] = (_Float16)0.f;
  }
  if (tid < BT) dins[tid] = 0.f;

  // Weight registers (shared pool between groups):
  //   group A (layer0): WA = Whh0 ;               wih0v = Wih0 col, biasv = b0
  //   group B (layer1): WA = Wih1 ; WB = Whh1 ;   biasv = b1
  f16x8 WAhi[4][2], WAlo[4][2], WBhi[4][2], WBlo[4][2];
  float biasv[4], wih0v[4];

  auto splitrow = [&](const float* p, f16x8& hi, f16x8& lo) {
    #pragma unroll
    for (int j = 0; j < 8; ++j) {
      float v = p[j];
      _Float16 h = (_Float16)v;
      hi[j] = h; lo[j] = (_Float16)(v - (float)h);
    }
  };
  auto loadA = [&](const float* Wih0_, const float* Whh0_, const float* b0_) {
    #pragma unroll
    for (int ti = 0; ti < 4; ++ti) {
      const int r = (ti * 4 + wg) * 16 + n;
      biasv[ti] = b0_[r];
      wih0v[ti] = Wih0_[r];
      #pragma unroll
      for (int kc = 0; kc < 2; ++kc)
        splitrow(Whh0_ + r * 64 + kc * 32 + q * 8, WAhi[ti][kc], WAlo[ti][kc]);
    }
  };
  auto loadB = [&](const float* Wih1_, const float* Whh1_, const float* b1_) {
    #pragma unroll
    for (int ti = 0; ti < 4; ++ti) {
      const int r = (ti * 4 + wg) * 16 + n;
      biasv[ti] = b1_[r];
      #pragma unroll
      for (int kc = 0; kc < 2; ++kc) {
        splitrow(Wih1_ + r * 64 + kc * 32 + q * 8, WAhi[ti][kc], WAlo[ti][kc]);
        splitrow(Whh1_ + r * 64 + kc * 32 + q * 8, WBhi[ti][kc], WBlo[ti][kc]);
      }
    }
  };

  if (wv < 4) loadA(eWih0, eWhh0, eb0);
  else        loadB(eWih1, eWhh1, eb1);

  f32x4 cst = {0.f, 0.f, 0.f, 0.f};   // c0 on group A, c1 on group B

  // layer0 step: h_new = lstm(x_in, h_prev) ; gates = bias + x*wih0 + h@WA^T
  auto stepA = [&](const _Float16* Hhi, const _Float16* Hlo,
                   _Float16* Ohi, _Float16* Olo, f32x4 xv) {
    const _Float16* hp = Hhi + n * HPAD;
    const _Float16* lp = Hlo + n * HPAD;
    f16x8 ah0 = *(const f16x8*)(hp + q * 8);
    f16x8 ah1 = *(const f16x8*)(hp + 32 + q * 8);
    f16x8 al0 = *(const f16x8*)(lp + q * 8);
    f16x8 al1 = *(const f16x8*)(lp + 32 + q * 8);
    f32x4 g[4];
    #pragma unroll
    for (int ti = 0; ti < 4; ++ti) {
      f32x4 a;
      #pragma unroll
      for (int r = 0; r < 4; ++r) a[r] = xv[r] * wih0v[ti] + biasv[ti];
      a = mm3(ah0, al0, WAhi[ti][0], WAlo[ti][0], a);
      a = mm3(ah1, al1, WAhi[ti][1], WAlo[ti][1], a);
      g[ti] = a;
    }
    #pragma unroll
    for (int r = 0; r < 4; ++r) {
      float c = sigf(g[1][r]) * cst[r] + sigf(g[0][r]) * tanh_fast(g[2][r]);
      cst[r] = c;
      float h = sigf(g[3][r]) * tanh_fast(c);
      _Float16 hi = (_Float16)h;
      Ohi[(q * 4 + r) * HPAD + wbase] = hi;
      Olo[(q * 4 + r) * HPAD + wbase] = (_Float16)(h - (float)hi);
    }
  };

  // layer1 step: gates = bias + h0@WA^T + h1@WB^T
  auto stepB = [&](const _Float16* H0hi, const _Float16* H0lo,
                   const _Float16* H1hi, const _Float16* H1lo,
                   _Float16* Ohi, _Float16* Olo) {
    const _Float16* p0h = H0hi + n * HPAD;
    const _Float16* p0l = H0lo + n * HPAD;
    const _Float16* p1h = H1hi + n * HPAD;
    const _Float16* p1l = H1lo + n * HPAD;
    f16x8 b0h0 = *(const f16x8*)(p0h + q * 8);
    f16x8 b0h1 = *(const f16x8*)(p0h + 32 + q * 8);
    f16x8 b0l0 = *(const f16x8*)(p0l + q * 8);
    f16x8 b0l1 = *(const f16x8*)(p0l + 32 + q * 8);
    f16x8 a1h0 = *(const f16x8*)(p1h + q * 8);
    f16x8 a1h1 = *(const f16x8*)(p1h + 32 + q * 8);
    f16x8 a1l0 = *(const f16x8*)(p1l + q * 8);
    f16x8 a1l1 = *(const f16x8*)(p1l + 32 + q * 8);
    f32x4 g[4];
    #pragma unroll
    for (int ti = 0; ti < 4; ++ti) {
      f32x4 a;
      #pragma unroll
      for (int r = 0; r < 4; ++r) a[r] = biasv[ti];
      a = mm3(b0h0, b0l0, WAhi[ti][0], WAlo[ti][0], a);
      a = mm3(b0h1, b0l1, WAhi[ti][1], WAlo[ti][1], a);
      a = mm3(a1h0, a1l0, WBhi[ti][0], WBlo[ti][0], a);
      a = mm3(a1h1, a1l1, WBhi[ti][1], WBlo[ti][1], a);
      g[ti] = a;
    }
    #pragma unroll
    for (int r = 0; r < 4; ++r) {
      float c = sigf(g[1][r]) * cst[r] + sigf(g[0][r]) * tanh_fast(g[2][r]);
      cst[r] = c;
      float h = sigf(g[3][r]) * tanh_fast(c);
      _Float16 hi = (_Float16)h;
      Ohi[(q * 4 + r) * HPAD + wbase] = hi;
      Olo[(q * 4 + r) * HPAD + wbase] = (_Float16)(h - (float)hi);
    }
  };

  __syncthreads();

  // ---- encoder, unrolled x2 with static parity ----
  // Invariants (from R3): slot s: A reads h0[(s&1)^1] writes h0[s&1];
  // B (t=s-1) reads h0[t&1], h1[(t&1)^1], writes h1[t&1].

  // s = 0 (even): A only. h0[1] is zeros.
  if (wv < 4) {
    f32x4 xv = *(const f32x4*)(xs + q * 4);
    stepA(h0hi[1], h0lo[1], h0hi[0], h0lo[0], xv);
  }
  __syncthreads();

  // s = 1..364 as 182 (odd, even) pairs — both groups always active.
  for (int s = 1; s <= 363; s += 2) {
    // slot s (odd): A h0[0]->h0[1] ; B(t even) h0[0],h1[1] -> h1[0]
    if (wv < 4) {
      f32x4 xv = *(const f32x4*)(xs + s * BT + q * 4);
      stepA(h0hi[0], h0lo[0], h0hi[1], h0lo[1], xv);
    } else {
      stepB(h0hi[0], h0lo[0], h1hi[1], h1lo[1], h1hi[0], h1lo[0]);
    }
    __syncthreads();
    // slot s+1 (even): A h0[1]->h0[0] ; B(t odd) h0[1],h1[0] -> h1[1]
    if (wv < 4) {
      f32x4 xv = *(const f32x4*)(xs + (s + 1) * BT + q * 4);
      stepA(h0hi[1], h0lo[1], h0hi[0], h0lo[0], xv);
    } else {
      stepB(h0hi[1], h0lo[1], h1hi[0], h1lo[0], h1hi[1], h1lo[1]);
    }
    __syncthreads();
  }

  // s = 365 (odd): A loads decoder weights (idle slot); B(t=364 even):
  // h0[0], h1[1] -> h1[0].
  if (wv < 4) loadA(dWih0, dWhh0, db0);
  else        stepB(h0hi[0], h0lo[0], h1hi[1], h1lo[1], h1hi[0], h1lo[0]);
  __syncthreads();

  // ---- decoder ---- (latest h0, h1 live in parity-0 buffers)
  if (wv >= 4) loadB(dWih1, dWhh1, db1);
  float fcw[16];
  #pragma unroll
  for (int j = 0; j < 16; ++j) fcw[j] = fcW[q * 16 + j];
  const float fcb0 = fcb[0];

  #pragma unroll 1
  for (int hz = 0; hz < HZ; ++hz) {
    const int p = hz & 1;           // latest state parity at step entry
    if (wv < 4) {
      f32x4 dv = *(const f32x4*)(dins + q * 4);
      stepA(h0hi[p], h0lo[p], h0hi[1 - p], h0lo[1 - p], dv);
    }
    __syncthreads();
    if (wv >= 4) {
      stepB(h0hi[1 - p], h0lo[1 - p], h1hi[p], h1lo[p], h1hi[1 - p], h1lo[1 - p]);
    }
    __syncthreads();
    if (wv == 0) {
      const _Float16* Hhi = h1hi[1 - p];
      const _Float16* Hlo = h1lo[1 - p];
      f16x8 hh0 = *(const f16x8*)(Hhi + n * HPAD + q * 16);
      f16x8 hh1 = *(const f16x8*)(Hhi + n * HPAD + q * 16 + 8);
      f16x8 hl0 = *(const f16x8*)(Hlo + n * HPAD + q * 16);
      f16x8 hl1 = *(const f16x8*)(Hlo + n * HPAD + q * 16 + 8);
      float pacc = 0.f;
      #pragma unroll
      for (int j = 0; j < 8; ++j) pacc += fcw[j] * ((float)hh0[j] + (float)hl0[j]);
      #pragma unroll
      for (int j = 0; j < 8; ++j) pacc += fcw[8 + j] * ((float)hh1[j] + (float)hl1[j]);
      pacc += __shfl_down(pacc, 32);
      pacc += __shfl_down(pacc, 16);
      if (lane < BT) {
        pacc += fcb0;
        out[(b0g + lane) * HZ + hz] = pacc;
        dins[lane] = pacc;
      }
    }
    __syncthreads();
  }
}

extern "C" void kernel_launch(void* const* d_in, const int* in_sizes, int n_in,
                              void* d_out, int out_size, void* d_ws, size_t ws_size,
                              hipStream_t stream) {
  (void)in_sizes; (void)n_in; (void)d_ws; (void)ws_size; (void)out_size;
  const float* x     = (const float*)d_in[0];
  const float* eWih0 = (const float*)d_in[1];
  const float* eWhh0 = (const float*)d_in[2];
  const float* eb0   = (const float*)d_in[3];
  const float* eWih1 = (const float*)d_in[4];
  const float* eWhh1 = (const float*)d_in[5];
  const float* eb1   = (const float*)d_in[6];
  const float* dWih0 = (const float*)d_in[7];
  const float* dWhh0 = (const float*)d_in[8];
  const float* db0   = (const float*)d_in[9];
  const float* dWih1 = (const float*)d_in[10];
  const float* dWhh1 = (const float*)d_in[11];
  const float* db1   = (const float*)d_in[12];
  const float* fcW   = (const float*)d_in[13];
  const float* fcb   = (const float*)d_in[14];
  float* out = (float*)d_out;

  dim3 grid(4096 / BT);   // 256 blocks = 1/CU
  dim3 block(512);        // 8 waves: 4 layer0 + 4 layer1
  hipLaunchKernelGGL(lstm_fused, grid, block, 0, stream,
                     x, eWih0, eWhh0, eb0, eWih1, eWhh1, eb1,
                     dWih0, dWhh0, db0, dWih1, dWhh1, db1, fcW, fcb, out);
}